// Round 1
// baseline (521.310 us; speedup 1.0000x reference)
//
#include <hip/hip_runtime.h>

typedef unsigned short u16;
typedef __attribute__((ext_vector_type(8))) __bf16 bf16x8;
typedef __attribute__((ext_vector_type(4))) float f32x4;

// ---------- helpers ----------
__device__ inline u16 f2bf(float f) {
    union { float f; unsigned u; } v; v.f = f;
    unsigned r = v.u + 0x7fffu + ((v.u >> 16) & 1u);
    return (u16)(r >> 16);
}
__device__ inline float bf2f(u16 h) {
    union { unsigned u; float f; } v; v.u = ((unsigned)h) << 16;
    return v.f;
}
__device__ inline f32x4 mfma16(bf16x8 a, bf16x8 b, f32x4 c) {
    return __builtin_amdgcn_mfma_f32_16x16x32_bf16(a, b, c, 0, 0, 0);
}
__device__ inline void gload_lds16(const u16* g, u16* l) {
    __builtin_amdgcn_global_load_lds(
        (const __attribute__((address_space(1))) void*)g,
        (__attribute__((address_space(3))) void*)l, 16, 0, 0);
}

// ---------- cast f32 -> bf16 (vectorized) ----------
__global__ __launch_bounds__(256) void cast_bf16_kernel(
    const float4* __restrict__ in, u16* __restrict__ out) {
    int i = blockIdx.x * 256 + threadIdx.x;
    float4 v = in[i];
    unsigned long long pk = (unsigned long long)f2bf(v.x)
        | ((unsigned long long)f2bf(v.y) << 16)
        | ((unsigned long long)f2bf(v.z) << 32)
        | ((unsigned long long)f2bf(v.w) << 48);
    *(unsigned long long*)(out + (size_t)i * 4) = pk;
}

// ---------- transpose + cast: in [2048][N] f32 -> out [N][2048] bf16 ----------
__global__ void transpose_cast_k(const float* __restrict__ in, u16* __restrict__ out, int N) {
    __shared__ float t[32][33];
    int n0 = blockIdx.x * 32, k0 = blockIdx.y * 32;
    int tx = threadIdx.x, ty = threadIdx.y;       // 32 x 8
#pragma unroll
    for (int r = 0; r < 32; r += 8)
        t[ty + r][tx] = in[(size_t)(k0 + ty + r) * N + n0 + tx];
    __syncthreads();
#pragma unroll
    for (int r = 0; r < 32; r += 8)
        out[(size_t)(n0 + ty + r) * 2048 + k0 + tx] = f2bf(t[tx][ty + r]);
}

// ---------- GEMM: C[M][N] = A[M][K] * Bt[N][K]^T (+bias), 128x128 tile ----------
// MODE 0: bf16 out + qkv bias; MODE 1: f32 out, no bias
template<int MODE>
__global__ __launch_bounds__(256) void gemm_bt(
    const u16* __restrict__ A, const u16* __restrict__ Bt,
    u16* __restrict__ Cb, float* __restrict__ Cf,
    const float* __restrict__ bq, const float* __restrict__ bk,
    const float* __restrict__ bv, int M, int N, int K)
{
    __shared__ alignas(16) u16 As[128 * 32];
    __shared__ alignas(16) u16 Bs[128 * 32];
    const int tid = threadIdx.x;
    const int lane = tid & 63;
    const int wv = tid >> 6, wr = wv >> 1, wc = wv & 1;
    const int fr = lane & 15, fg = lane >> 4;
    const int m0 = blockIdx.y * 128, n0 = blockIdx.x * 128;
    const int srow = tid >> 2, scol = (tid & 3) * 8;
    const u16* Ag = A + (size_t)(m0 + srow) * K + scol;
    const u16* Bg = Bt + (size_t)(n0 + srow) * K + scol;
    f32x4 acc[4][4] = {};
    for (int kt = 0; kt < K; kt += 32) {
        gload_lds16(Ag + kt, &As[tid * 8]);
        gload_lds16(Ag + (size_t)64 * K + kt, &As[2048 + tid * 8]);
        gload_lds16(Bg + kt, &Bs[tid * 8]);
        gload_lds16(Bg + (size_t)64 * K + kt, &Bs[2048 + tid * 8]);
        asm volatile("s_waitcnt vmcnt(0)" ::: "memory");
        __syncthreads();
        bf16x8 af[4], bfv[4];
#pragma unroll
        for (int m = 0; m < 4; ++m)
            af[m] = *(const bf16x8*)&As[(wr * 64 + m * 16 + fr) * 32 + fg * 8];
#pragma unroll
        for (int n = 0; n < 4; ++n)
            bfv[n] = *(const bf16x8*)&Bs[(wc * 64 + n * 16 + fr) * 32 + fg * 8];
#pragma unroll
        for (int m = 0; m < 4; ++m)
#pragma unroll
            for (int n = 0; n < 4; ++n)
                acc[m][n] = mfma16(af[m], bfv[n], acc[m][n]);
        __syncthreads();
    }
#pragma unroll
    for (int m = 0; m < 4; ++m) {
#pragma unroll
        for (int n = 0; n < 4; ++n) {
#pragma unroll
            for (int r = 0; r < 4; ++r) {
                int row = m0 + wr * 64 + m * 16 + fg * 4 + r;
                int col = n0 + wc * 64 + n * 16 + fr;
                float v = acc[m][n][r];
                if (MODE == 0) {
                    float bias = (col < 2048) ? bq[col]
                               : (col < 2560) ? bk[col - 2048] : bv[col - 2560];
                    Cb[(size_t)row * N + col] = f2bf(v + bias);
                } else {
                    Cf[(size_t)row * N + col] = v;
                }
            }
        }
    }
}

// ---------- RoPE + relayout ----------
// qkvb [B*S][3072] bf16 -> Qs [B][16][S][128] (scaled 1/sqrt(128)),
// Ks [B][4][S][128], Vt [B][4][128][S]
__global__ __launch_bounds__(256) void rope_layout_kernel(
    const u16* __restrict__ qkvb, const int* __restrict__ pos_ids,
    u16* __restrict__ Qs, u16* __restrict__ Ks, u16* __restrict__ Vt)
{
    const int bs = blockIdx.x;
    const int b = bs >> 11, s = bs & 2047;
    const int tid = threadIdx.x;
    const int d = tid & 63, tq = tid >> 6;
    const float pos = (float)pos_ids[bs];
    // inv_freq = 10000^(-d/64) = exp(-d * ln(10000)/64)
    const float ang = pos * __expf(-(float)d * 0.1439115683121279f);
    const float sa = sinf(ang), ca = cosf(ang);
    const u16* base = qkvb + (size_t)bs * 3072;
    const float qscale = 0.08838834764831845f;   // 1/sqrt(128)
#pragma unroll
    for (int it = 0; it < 4; ++it) {
        int hh = it * 4 + tq;
        float xlo = bf2f(base[hh * 128 + d]);
        float xhi = bf2f(base[hh * 128 + 64 + d]);
        size_t qb = ((size_t)(b * 16 + hh) * 2048 + s) * 128;
        Qs[qb + d]      = f2bf((xlo * ca - xhi * sa) * qscale);
        Qs[qb + 64 + d] = f2bf((xhi * ca + xlo * sa) * qscale);
    }
    {
        int hh = tq;
        float xlo = bf2f(base[2048 + hh * 128 + d]);
        float xhi = bf2f(base[2048 + hh * 128 + 64 + d]);
        size_t kb = ((size_t)(b * 4 + hh) * 2048 + s) * 128;
        Ks[kb + d]      = f2bf(xlo * ca - xhi * sa);
        Ks[kb + 64 + d] = f2bf(xhi * ca + xlo * sa);
    }
#pragma unroll
    for (int it = 0; it < 2; ++it) {
        int e = it * 256 + tid;
        int hh = e >> 7, dd = e & 127;
        Vt[((size_t)(b * 4 + hh) * 128 + dd) * 2048 + s] = base[2560 + e];
    }
}

// ---------- flash attention, sliding window 1024, GQA 4:1 ----------
// 1 wave = 16 q rows; block = 4 waves = 64 q rows; grid (32, 16, 2)
__global__ __launch_bounds__(256) void attn_kernel(
    const u16* __restrict__ Qs, const u16* __restrict__ Ks,
    const u16* __restrict__ Vt, u16* __restrict__ Aout)
{
    __shared__ alignas(16) u16 P_lds[4][512];
    const int tid = threadIdx.x;
    const int lane = tid & 63, w = tid >> 6;
    const int fr = lane & 15, fg = lane >> 4;
    const int h = blockIdx.y, b = blockIdx.z;
    const int kvh = h >> 2;
    const int q0 = blockIdx.x * 64 + w * 16;
    const u16* Qb = Qs + ((size_t)(b * 16 + h) * 2048) * 128;
    const u16* Kb = Ks + ((size_t)(b * 4 + kvh) * 2048) * 128;
    const u16* Vb = Vt + ((size_t)(b * 4 + kvh) * 128) * 2048;
    bf16x8 qf[4];
#pragma unroll
    for (int dd = 0; dd < 4; ++dd)
        qf[dd] = *(const bf16x8*)&Qb[(size_t)(q0 + fr) * 128 + dd * 32 + fg * 8];
    f32x4 oacc[8] = {};
    float mrow[4], lrow[4];
#pragma unroll
    for (int r = 0; r < 4; ++r) { mrow[r] = -1e30f; lrow[r] = 0.f; }
    const int iBase = q0 + fg * 4;
    int k_start = q0 - 1024; if (k_start < 0) k_start = 0;
    k_start &= ~31;
    u16* pl = P_lds[w];
    for (int kt = k_start; kt <= q0 + 15; kt += 32) {
        f32x4 s0 = {0.f, 0.f, 0.f, 0.f}, s1 = {0.f, 0.f, 0.f, 0.f};
#pragma unroll
        for (int dd = 0; dd < 4; ++dd) {
            bf16x8 kf0 = *(const bf16x8*)&Kb[(size_t)(kt + fr) * 128 + dd * 32 + fg * 8];
            bf16x8 kf1 = *(const bf16x8*)&Kb[(size_t)(kt + 16 + fr) * 128 + dd * 32 + fg * 8];
            s0 = mfma16(qf[dd], kf0, s0);
            s1 = mfma16(qf[dd], kf1, s1);
        }
        const int j0 = kt + fr, j1 = j0 + 16;
        float p0[4], p1[4], scl[4];
#pragma unroll
        for (int r = 0; r < 4; ++r) {
            const int i = iBase + r;
            float v0 = (j0 <= i && j0 + 1024 >= i) ? s0[r] : -1e30f;
            float v1 = (j1 <= i && j1 + 1024 >= i) ? s1[r] : -1e30f;
            float e = fmaxf(v0, v1);
            e = fmaxf(e, __shfl_xor(e, 1, 16));
            e = fmaxf(e, __shfl_xor(e, 2, 16));
            e = fmaxf(e, __shfl_xor(e, 4, 16));
            e = fmaxf(e, __shfl_xor(e, 8, 16));
            float mn = fmaxf(mrow[r], e);
            scl[r] = __expf(mrow[r] - mn);
            p0[r] = __expf(v0 - mn);
            p1[r] = __expf(v1 - mn);
            float rs = p0[r] + p1[r];
            rs += __shfl_xor(rs, 1, 16);
            rs += __shfl_xor(rs, 2, 16);
            rs += __shfl_xor(rs, 4, 16);
            rs += __shfl_xor(rs, 8, 16);
            lrow[r] = lrow[r] * scl[r] + rs;
            mrow[r] = mn;
        }
#pragma unroll
        for (int t = 0; t < 8; ++t)
#pragma unroll
            for (int r = 0; r < 4; ++r) oacc[t][r] *= scl[r];
        // P (D-layout) -> LDS [16 rows][32 cols]
#pragma unroll
        for (int r = 0; r < 4; ++r) {
            pl[(fg * 4 + r) * 32 + fr]      = f2bf(p0[r]);
            pl[(fg * 4 + r) * 32 + 16 + fr] = f2bf(p1[r]);
        }
        asm volatile("s_waitcnt lgkmcnt(0)" ::: "memory");
        __builtin_amdgcn_sched_barrier(0);
        bf16x8 pa = *(const bf16x8*)&pl[fr * 32 + fg * 8];   // A-layout read
#pragma unroll
        for (int dt = 0; dt < 8; ++dt) {
            bf16x8 vf = *(const bf16x8*)&Vb[(size_t)(dt * 16 + fr) * 2048 + kt + fg * 8];
            oacc[dt] = mfma16(pa, vf, oacc[dt]);
        }
    }
    float inv[4];
#pragma unroll
    for (int r = 0; r < 4; ++r) inv[r] = 1.0f / lrow[r];
#pragma unroll
    for (int dt = 0; dt < 8; ++dt)
#pragma unroll
        for (int r = 0; r < 4; ++r) {
            size_t row = (size_t)b * 2048 + q0 + fg * 4 + r;
            Aout[row * 2048 + h * 128 + dt * 16 + fr] = f2bf(oacc[dt][r] * inv[r]);
        }
}

// ---------- launch ----------
extern "C" void kernel_launch(void* const* d_in, const int* in_sizes, int n_in,
                              void* d_out, int out_size, void* d_ws, size_t ws_size,
                              hipStream_t stream) {
    const float* hs  = (const float*)d_in[0];
    const int*   pos = (const int*)d_in[2];
    const float* Wq  = (const float*)d_in[3];
    const float* bq  = (const float*)d_in[4];
    const float* Wk  = (const float*)d_in[5];
    const float* bk  = (const float*)d_in[6];
    const float* Wv  = (const float*)d_in[7];
    const float* bv  = (const float*)d_in[8];
    const float* Wo  = (const float*)d_in[9];
    float* out = (float*)d_out;
    char* ws = (char*)d_ws;

    u16* hsb   = (u16*)(ws);                       // [4096][2048]      16.78 MB
    u16* WqkvT = (u16*)(ws + 16777216);            // [3072][2048]      12.58 MB
    u16* WoT   = (u16*)(ws + 29360128);            // [2048][2048]       8.39 MB
    u16* qkvb  = (u16*)(ws + 37748736);            // [4096][3072]      25.17 MB
    u16* Qs    = (u16*)(ws + 62914560);            // [2][16][2048][128] 16.78 MB
    u16* Ks    = (u16*)(ws + 79691776);            // [2][4][2048][128]  4.19 MB
    u16* Vt    = (u16*)(ws + 83886080);            // [2][4][128][2048]  4.19 MB
    u16* aout  = (u16*)(ws + 88080384);            // [4096][2048]      16.78 MB

    cast_bf16_kernel<<<8192, 256, 0, stream>>>((const float4*)hs, hsb);
    transpose_cast_k<<<dim3(64, 64), dim3(32, 8), 0, stream>>>(Wq, WqkvT, 2048);
    transpose_cast_k<<<dim3(16, 64), dim3(32, 8), 0, stream>>>(Wk, WqkvT + (size_t)2048 * 2048, 512);
    transpose_cast_k<<<dim3(16, 64), dim3(32, 8), 0, stream>>>(Wv, WqkvT + (size_t)2560 * 2048, 512);
    transpose_cast_k<<<dim3(64, 64), dim3(32, 8), 0, stream>>>(Wo, WoT, 2048);

    gemm_bt<0><<<dim3(24, 32), 256, 0, stream>>>(hsb, WqkvT, qkvb, nullptr,
                                                 bq, bk, bv, 4096, 3072, 2048);
    rope_layout_kernel<<<4096, 256, 0, stream>>>(qkvb, pos, Qs, Ks, Vt);
    attn_kernel<<<dim3(32, 16, 2), 256, 0, stream>>>(Qs, Ks, Vt, aout);
    gemm_bt<1><<<dim3(16, 32), 256, 0, stream>>>(aout, WoT, nullptr, out,
                                                 nullptr, nullptr, nullptr, 4096, 2048, 2048);
}

// Round 3
// 364.309 us; speedup vs baseline: 1.4310x; 1.4310x over previous
//
#include <hip/hip_runtime.h>

typedef unsigned short u16;
typedef __attribute__((ext_vector_type(8))) __bf16 bf16x8;
typedef __attribute__((ext_vector_type(8))) unsigned short u16x8;
typedef __attribute__((ext_vector_type(4))) float f32x4;

// ---------- helpers ----------
__device__ inline u16 f2bf(float f) {
    union { float f; unsigned u; } v; v.f = f;
    unsigned r = v.u + 0x7fffu + ((v.u >> 16) & 1u);
    return (u16)(r >> 16);
}
__device__ inline float bf2f(u16 h) {
    union { unsigned u; float f; } v; v.u = ((unsigned)h) << 16;
    return v.f;
}
__device__ inline f32x4 mfma16(bf16x8 a, bf16x8 b, f32x4 c) {
    return __builtin_amdgcn_mfma_f32_16x16x32_bf16(a, b, c, 0, 0, 0);
}
__device__ inline void gload_lds16(const u16* g, u16* l) {
    __builtin_amdgcn_global_load_lds(
        (const __attribute__((address_space(1))) void*)g,
        (__attribute__((address_space(3))) void*)l, 16, 0, 0);
}

// ---------- cast f32 -> bf16 (vectorized) ----------
__global__ __launch_bounds__(256) void cast_bf16_kernel(
    const float4* __restrict__ in, u16* __restrict__ out) {
    int i = blockIdx.x * 256 + threadIdx.x;
    float4 v = in[i];
    unsigned long long pk = (unsigned long long)f2bf(v.x)
        | ((unsigned long long)f2bf(v.y) << 16)
        | ((unsigned long long)f2bf(v.z) << 32)
        | ((unsigned long long)f2bf(v.w) << 48);
    *(unsigned long long*)(out + (size_t)i * 4) = pk;
}

// ---------- transpose + cast: in [2048][N] f32 -> out [N][2048] bf16 ----------
__global__ void transpose_cast_k(const float* __restrict__ in, u16* __restrict__ out, int N) {
    __shared__ float t[32][33];
    int n0 = blockIdx.x * 32, k0 = blockIdx.y * 32;
    int tx = threadIdx.x, ty = threadIdx.y;       // 32 x 8
#pragma unroll
    for (int r = 0; r < 32; r += 8)
        t[ty + r][tx] = in[(size_t)(k0 + ty + r) * N + n0 + tx];
    __syncthreads();
#pragma unroll
    for (int r = 0; r < 32; r += 8)
        out[(size_t)(n0 + ty + r) * 2048 + k0 + tx] = f2bf(t[tx][ty + r]);
}

// ---------- GEMM: C[M][N] = A[M][K] * Bt[N][K]^T (+bias), 128x128 tile ----------
template<int MODE>
__global__ __launch_bounds__(256) void gemm_bt(
    const u16* __restrict__ A, const u16* __restrict__ Bt,
    u16* __restrict__ Cb, float* __restrict__ Cf,
    const float* __restrict__ bq, const float* __restrict__ bk,
    const float* __restrict__ bv, int M, int N, int K)
{
    __shared__ alignas(16) u16 As[128 * 32];
    __shared__ alignas(16) u16 Bs[128 * 32];
    const int tid = threadIdx.x;
    const int lane = tid & 63;
    const int wv = tid >> 6, wr = wv >> 1, wc = wv & 1;
    const int fr = lane & 15, fg = lane >> 4;
    const int m0 = blockIdx.y * 128, n0 = blockIdx.x * 128;
    const int srow = tid >> 2, scol = (tid & 3) * 8;
    const u16* Ag = A + (size_t)(m0 + srow) * K + scol;
    const u16* Bg = Bt + (size_t)(n0 + srow) * K + scol;
    f32x4 acc[4][4] = {};
    for (int kt = 0; kt < K; kt += 32) {
        gload_lds16(Ag + kt, &As[tid * 8]);
        gload_lds16(Ag + (size_t)64 * K + kt, &As[2048 + tid * 8]);
        gload_lds16(Bg + kt, &Bs[tid * 8]);
        gload_lds16(Bg + (size_t)64 * K + kt, &Bs[2048 + tid * 8]);
        asm volatile("s_waitcnt vmcnt(0)" ::: "memory");
        __syncthreads();
        bf16x8 af[4], bfv[4];
#pragma unroll
        for (int m = 0; m < 4; ++m)
            af[m] = *(const bf16x8*)&As[(wr * 64 + m * 16 + fr) * 32 + fg * 8];
#pragma unroll
        for (int n = 0; n < 4; ++n)
            bfv[n] = *(const bf16x8*)&Bs[(wc * 64 + n * 16 + fr) * 32 + fg * 8];
#pragma unroll
        for (int m = 0; m < 4; ++m)
#pragma unroll
            for (int n = 0; n < 4; ++n)
                acc[m][n] = mfma16(af[m], bfv[n], acc[m][n]);
        __syncthreads();
    }
#pragma unroll
    for (int m = 0; m < 4; ++m) {
#pragma unroll
        for (int n = 0; n < 4; ++n) {
#pragma unroll
            for (int r = 0; r < 4; ++r) {
                int row = m0 + wr * 64 + m * 16 + fg * 4 + r;
                int col = n0 + wc * 64 + n * 16 + fr;
                float v = acc[m][n][r];
                if (MODE == 0) {
                    float bias = (col < 2048) ? bq[col]
                               : (col < 2560) ? bk[col - 2048] : bv[col - 2560];
                    Cb[(size_t)row * N + col] = f2bf(v + bias);
                } else {
                    Cf[(size_t)row * N + col] = v;
                }
            }
        }
    }
}

// ---------- RoPE + relayout (Q, K only) ----------
__global__ __launch_bounds__(256) void rope_layout_kernel(
    const u16* __restrict__ qkvb, const int* __restrict__ pos_ids,
    u16* __restrict__ Qs, u16* __restrict__ Ks)
{
    const int bs = blockIdx.x;
    const int b = bs >> 11, s = bs & 2047;
    const int tid = threadIdx.x;
    const int d = tid & 63, tq = tid >> 6;
    const float pos = (float)pos_ids[bs];
    const float ang = pos * __expf(-(float)d * 0.1439115683121279f);
    const float sa = sinf(ang), ca = cosf(ang);
    const u16* base = qkvb + (size_t)bs * 3072;
    const float qscale = 0.08838834764831845f;   // 1/sqrt(128)
#pragma unroll
    for (int it = 0; it < 4; ++it) {
        int hh = it * 4 + tq;
        float xlo = bf2f(base[hh * 128 + d]);
        float xhi = bf2f(base[hh * 128 + 64 + d]);
        size_t qb = ((size_t)(b * 16 + hh) * 2048 + s) * 128;
        Qs[qb + d]      = f2bf((xlo * ca - xhi * sa) * qscale);
        Qs[qb + 64 + d] = f2bf((xhi * ca + xlo * sa) * qscale);
    }
    {
        int hh = tq;
        float xlo = bf2f(base[2048 + hh * 128 + d]);
        float xhi = bf2f(base[2048 + hh * 128 + 64 + d]);
        size_t kb = ((size_t)(b * 4 + hh) * 2048 + s) * 128;
        Ks[kb + d]      = f2bf(xlo * ca - xhi * sa);
        Ks[kb + 64 + d] = f2bf(xhi * ca + xlo * sa);
    }
}

// ---------- V transpose: qkvb[.][2560+h*128+d] -> Vt [B][4][128][S] ----------
__global__ __launch_bounds__(256) void v_transpose_kernel(
    const u16* __restrict__ qkvb, u16* __restrict__ Vt)
{
    __shared__ u16 tl[64][136];
    const int s0 = blockIdx.x * 64, hh = blockIdx.y, b = blockIdx.z;
    const int tid = threadIdx.x;
    {
        const int r = tid >> 4, c = (tid & 15) * 8;
        const u16* src = qkvb + (size_t)(b * 2048 + s0) * 3072 + 2560 + hh * 128 + c;
#pragma unroll
        for (int i = 0; i < 4; ++i)
            *(bf16x8*)&tl[i * 16 + r][c] = *(const bf16x8*)&src[(size_t)(i * 16 + r) * 3072];
    }
    __syncthreads();
    {
        const int d = tid >> 3, sc = (tid & 7) * 8;
        u16* dst = Vt + ((size_t)(b * 4 + hh) * 128) * 2048 + s0;
#pragma unroll
        for (int i = 0; i < 4; ++i) {
            u16x8 vv;
#pragma unroll
            for (int e = 0; e < 8; ++e) vv[e] = tl[sc + e][i * 32 + d];
            *(u16x8*)&dst[(size_t)(i * 32 + d) * 2048 + sc] = vv;
        }
    }
}

// ---------- flash attention: block = 128 q rows (4 waves x 32), KVBLK=64 ----------
// K/V double-buffered in LDS (XOR-swizzled), 2-phase pipeline. grid (16,16,2)
__global__ __launch_bounds__(256, 2) void attn_kernel(
    const u16* __restrict__ Qs, const u16* __restrict__ Ks,
    const u16* __restrict__ Vt, u16* __restrict__ Aout)
{
    __shared__ alignas(16) u16 Klds[2][64 * 128];   // [kv row][d], swizzled
    __shared__ alignas(16) u16 Vlds[2][128 * 64];   // [d][kv], swizzled
    __shared__ alignas(16) u16 Plds[4][32 * 64];    // per-wave P, swizzled
    const int tid = threadIdx.x;
    const int lane = tid & 63, w = tid >> 6;
    const int fr = lane & 15, fg = lane >> 4;
    const int h = blockIdx.y, b = blockIdx.z;
    const int kvh = h >> 2;
    const int q0b = blockIdx.x * 128;
    const int q0w = q0b + w * 32;
    const u16* Qb = Qs + ((size_t)(b * 16 + h) * 2048) * 128;
    const u16* Kb = Ks + ((size_t)(b * 4 + kvh) * 2048) * 128;
    const u16* Vb = Vt + ((size_t)(b * 4 + kvh) * 128) * 2048;

    // staging: pre-swizzled global source, linear LDS dest (guideline 21)
    const int ksrow = tid >> 4;                           // K row within 16-chunk
    const int kscol = ((tid & 15) ^ (ksrow & 7)) * 8;     // swizzled src col (u16)
    const int vsrow = tid >> 3;                           // V d-row within 32-chunk
    const int vscol = ((tid & 7) ^ (vsrow & 7)) * 8;

    bf16x8 qf[2][4];
#pragma unroll
    for (int m = 0; m < 2; ++m)
#pragma unroll
        for (int dd = 0; dd < 4; ++dd)
            qf[m][dd] = *(const bf16x8*)&Qb[(size_t)(q0w + m * 16 + fr) * 128 + dd * 32 + fg * 8];

    f32x4 oacc[2][8] = {};
    float mrow[2][4], lrow[2][4];
#pragma unroll
    for (int m = 0; m < 2; ++m)
#pragma unroll
        for (int r = 0; r < 4; ++r) { mrow[m][r] = -1e30f; lrow[m][r] = 0.f; }

    int k_lo = q0b - 1024; if (k_lo < 0) k_lo = 0;        // 64-aligned
    const int NT = (q0b + 64 - k_lo) / 64 + 1;

#define STAGE(buf, kt)                                                          \
    {                                                                           \
        _Pragma("unroll")                                                       \
        for (int i = 0; i < 4; ++i)                                             \
            gload_lds16(Kb + (size_t)((kt) + i * 16 + ksrow) * 128 + kscol,     \
                        &Klds[buf][(i * 16 + ksrow) * 128 + (tid & 15) * 8]);   \
        _Pragma("unroll")                                                       \
        for (int i = 0; i < 4; ++i)                                             \
            gload_lds16(Vb + (size_t)(i * 32 + vsrow) * 2048 + (kt) + vscol,    \
                        &Vlds[buf][(i * 32 + vsrow) * 64 + (tid & 7) * 8]);     \
    }

    int cur = 0;
    STAGE(0, k_lo);
    asm volatile("s_waitcnt vmcnt(0)" ::: "memory");
    __syncthreads();

    for (int t = 0; t < NT; ++t) {
        const int kt = k_lo + t * 64;
        if (t + 1 < NT) STAGE(cur ^ 1, kt + 64);
        const bool active = (kt <= q0w + 31) && (kt + 63 >= q0w - 1024);
        if (active) {
            const u16* Kl = &Klds[cur][0];
            const u16* Vl = &Vlds[cur][0];
            u16* Pl = &Plds[w][0];
            // ---- QK^T ----
            f32x4 s[2][4] = {};
#pragma unroll
            for (int ko = 0; ko < 4; ++ko) {
                const int krow = ko * 16 + fr;
                const int swk = (krow & 7) * 8;
                bf16x8 kf[4];
#pragma unroll
                for (int dd = 0; dd < 4; ++dd)
                    kf[dd] = *(const bf16x8*)&Kl[krow * 128 + ((dd * 32 + fg * 8) ^ swk)];
#pragma unroll
                for (int m = 0; m < 2; ++m)
#pragma unroll
                    for (int dd = 0; dd < 4; ++dd)
                        s[m][ko] = mfma16(qf[m][dd], kf[dd], s[m][ko]);
            }
            // ---- online softmax + P write ----
#pragma unroll
            for (int m = 0; m < 2; ++m) {
                float scl[4];
#pragma unroll
                for (int r = 0; r < 4; ++r) {
                    const int i = q0w + m * 16 + fg * 4 + r;
                    float v[4]; bool val[4];
#pragma unroll
                    for (int ko = 0; ko < 4; ++ko) {
                        const int j = kt + ko * 16 + fr;
                        val[ko] = (j <= i) && (j + 1024 >= i);
                        v[ko] = val[ko] ? s[m][ko][r] : -1e30f;
                    }
                    float e = fmaxf(fmaxf(v[0], v[1]), fmaxf(v[2], v[3]));
                    e = fmaxf(e, __shfl_xor(e, 1, 16));
                    e = fmaxf(e, __shfl_xor(e, 2, 16));
                    e = fmaxf(e, __shfl_xor(e, 4, 16));
                    e = fmaxf(e, __shfl_xor(e, 8, 16));
                    const float mo = mrow[m][r];
                    const float mn = fmaxf(mo, e);
                    const float sc = __expf(mo - mn);
                    float p[4], rs = 0.f;
#pragma unroll
                    for (int ko = 0; ko < 4; ++ko) {
                        p[ko] = val[ko] ? __expf(v[ko] - mn) : 0.f;
                        rs += p[ko];
                    }
                    rs += __shfl_xor(rs, 1, 16);
                    rs += __shfl_xor(rs, 2, 16);
                    rs += __shfl_xor(rs, 4, 16);
                    rs += __shfl_xor(rs, 8, 16);
                    lrow[m][r] = lrow[m][r] * sc + rs;
                    mrow[m][r] = mn;
                    scl[r] = sc;
                    const int prow = m * 16 + fg * 4 + r;
                    const int swp = (prow & 7) * 8;
#pragma unroll
                    for (int ko = 0; ko < 4; ++ko)
                        Pl[prow * 64 + ((ko * 16 + fr) ^ swp)] = f2bf(p[ko]);
                }
#pragma unroll
                for (int dt = 0; dt < 8; ++dt)
#pragma unroll
                    for (int r = 0; r < 4; ++r) oacc[m][dt][r] *= scl[r];
            }
            asm volatile("s_waitcnt lgkmcnt(0)" ::: "memory");
            __builtin_amdgcn_sched_barrier(0);
            // ---- PV ----
            bf16x8 pa[2][2];
#pragma unroll
            for (int m = 0; m < 2; ++m) {
                const int prow = m * 16 + fr;
                const int swp = (prow & 7) * 8;
#pragma unroll
                for (int ks = 0; ks < 2; ++ks)
                    pa[m][ks] = *(const bf16x8*)&Pl[prow * 64 + ((ks * 32 + fg * 8) ^ swp)];
            }
#pragma unroll
            for (int ks = 0; ks < 2; ++ks)
#pragma unroll
                for (int dt = 0; dt < 8; ++dt) {
                    const int vrow = dt * 16 + fr;
                    const int swv = (vrow & 7) * 8;
                    bf16x8 vf = *(const bf16x8*)&Vl[vrow * 64 + ((ks * 32 + fg * 8) ^ swv)];
#pragma unroll
                    for (int m = 0; m < 2; ++m)
                        oacc[m][dt] = mfma16(pa[m][ks], vf, oacc[m][dt]);
                }
        }
        asm volatile("s_waitcnt vmcnt(0)" ::: "memory");
        __syncthreads();
        cur ^= 1;
    }
#undef STAGE

#pragma unroll
    for (int m = 0; m < 2; ++m) {
        float inv[4];
#pragma unroll
        for (int r = 0; r < 4; ++r) inv[r] = 1.0f / lrow[m][r];
#pragma unroll
        for (int dt = 0; dt < 8; ++dt)
#pragma unroll
            for (int r = 0; r < 4; ++r) {
                const size_t row = (size_t)b * 2048 + q0w + m * 16 + fg * 4 + r;
                Aout[row * 2048 + h * 128 + dt * 16 + fr] = f2bf(oacc[m][dt][r] * inv[r]);
            }
    }
}

// ---------- launch ----------
extern "C" void kernel_launch(void* const* d_in, const int* in_sizes, int n_in,
                              void* d_out, int out_size, void* d_ws, size_t ws_size,
                              hipStream_t stream) {
    const float* hs  = (const float*)d_in[0];
    const int*   pos = (const int*)d_in[2];
    const float* Wq  = (const float*)d_in[3];
    const float* bq  = (const float*)d_in[4];
    const float* Wk  = (const float*)d_in[5];
    const float* bk  = (const float*)d_in[6];
    const float* Wv  = (const float*)d_in[7];
    const float* bv  = (const float*)d_in[8];
    const float* Wo  = (const float*)d_in[9];
    float* out = (float*)d_out;
    char* ws = (char*)d_ws;

    u16* hsb   = (u16*)(ws);                       // [4096][2048]
    u16* WqkvT = (u16*)(ws + 16777216);            // [3072][2048]
    u16* WoT   = (u16*)(ws + 29360128);            // [2048][2048]
    u16* qkvb  = (u16*)(ws + 37748736);            // [4096][3072]
    u16* Qs    = (u16*)(ws + 62914560);            // [2][16][2048][128]
    u16* Ks    = (u16*)(ws + 79691776);            // [2][4][2048][128]
    u16* Vt    = (u16*)(ws + 83886080);            // [2][4][128][2048]
    u16* aout  = (u16*)(ws + 88080384);            // [4096][2048]

    cast_bf16_kernel<<<8192, 256, 0, stream>>>((const float4*)hs, hsb);
    transpose_cast_k<<<dim3(64, 64), dim3(32, 8), 0, stream>>>(Wq, WqkvT, 2048);
    transpose_cast_k<<<dim3(16, 64), dim3(32, 8), 0, stream>>>(Wk, WqkvT + (size_t)2048 * 2048, 512);
    transpose_cast_k<<<dim3(16, 64), dim3(32, 8), 0, stream>>>(Wv, WqkvT + (size_t)2560 * 2048, 512);
    transpose_cast_k<<<dim3(64, 64), dim3(32, 8), 0, stream>>>(Wo, WoT, 2048);

    gemm_bt<0><<<dim3(24, 32), 256, 0, stream>>>(hsb, WqkvT, qkvb, nullptr,
                                                 bq, bk, bv, 4096, 3072, 2048);
    rope_layout_kernel<<<4096, 256, 0, stream>>>(qkvb, pos, Qs, Ks);
    v_transpose_kernel<<<dim3(32, 4, 2), 256, 0, stream>>>(qkvb, Vt);
    attn_kernel<<<dim3(16, 16, 2), 256, 0, stream>>>(Qs, Ks, Vt, aout);
    gemm_bt<1><<<dim3(16, 32), 256, 0, stream>>>(aout, WoT, nullptr, out,
                                                 nullptr, nullptr, nullptr, 4096, 2048, 2048);
}

// Round 4
// 336.603 us; speedup vs baseline: 1.5487x; 1.0823x over previous
//
#include <hip/hip_runtime.h>

typedef unsigned short u16;
typedef unsigned int u32;
typedef __attribute__((ext_vector_type(8))) __bf16 bf16x8;
typedef __attribute__((ext_vector_type(8))) unsigned short u16x8;
typedef __attribute__((ext_vector_type(4))) unsigned short u16x4;
typedef __attribute__((ext_vector_type(4))) unsigned int u32x4;
typedef __attribute__((ext_vector_type(4))) float f32x4;
typedef __attribute__((ext_vector_type(16))) float f32x16;

// ---------- helpers ----------
__device__ inline u16 f2bf(float f) {
    union { float f; unsigned u; } v; v.f = f;
    unsigned r = v.u + 0x7fffu + ((v.u >> 16) & 1u);
    return (u16)(r >> 16);
}
__device__ inline float bf2f(u16 h) {
    union { unsigned u; float f; } v; v.u = ((unsigned)h) << 16;
    return v.f;
}
__device__ inline f32x4 mfma16(bf16x8 a, bf16x8 b, f32x4 c) {
    return __builtin_amdgcn_mfma_f32_16x16x32_bf16(a, b, c, 0, 0, 0);
}
__device__ inline f32x16 mfma32(bf16x8 a, bf16x8 b, f32x16 c) {
    return __builtin_amdgcn_mfma_f32_32x32x16_bf16(a, b, c, 0, 0, 0);
}
__device__ inline void gload_lds16(const u16* g, u16* l) {
    __builtin_amdgcn_global_load_lds(
        (const __attribute__((address_space(1))) void*)g,
        (__attribute__((address_space(3))) void*)l, 16, 0, 0);
}

// ---------- cast f32 -> bf16 (vectorized) ----------
__global__ __launch_bounds__(256) void cast_bf16_kernel(
    const float4* __restrict__ in, u16* __restrict__ out) {
    int i = blockIdx.x * 256 + threadIdx.x;
    float4 v = in[i];
    unsigned long long pk = (unsigned long long)f2bf(v.x)
        | ((unsigned long long)f2bf(v.y) << 16)
        | ((unsigned long long)f2bf(v.z) << 32)
        | ((unsigned long long)f2bf(v.w) << 48);
    *(unsigned long long*)(out + (size_t)i * 4) = pk;
}

// ---------- transpose + cast: in [2048][N] f32 -> out [N][2048] bf16 ----------
__global__ void transpose_cast_k(const float* __restrict__ in, u16* __restrict__ out, int N) {
    __shared__ float t[32][33];
    int n0 = blockIdx.x * 32, k0 = blockIdx.y * 32;
    int tx = threadIdx.x, ty = threadIdx.y;       // 32 x 8
#pragma unroll
    for (int r = 0; r < 32; r += 8)
        t[ty + r][tx] = in[(size_t)(k0 + ty + r) * N + n0 + tx];
    __syncthreads();
#pragma unroll
    for (int r = 0; r < 32; r += 8)
        out[(size_t)(n0 + ty + r) * 2048 + k0 + tx] = f2bf(t[tx][ty + r]);
}

// ---------- GEMM: C[M][N] = A[M][K] * Bt[N][K]^T (+bias), 128x128 tile ----------
template<int MODE>
__global__ __launch_bounds__(256) void gemm_bt(
    const u16* __restrict__ A, const u16* __restrict__ Bt,
    u16* __restrict__ Cb, float* __restrict__ Cf,
    const float* __restrict__ bq, const float* __restrict__ bk,
    const float* __restrict__ bv, int M, int N, int K)
{
    __shared__ alignas(16) u16 As[128 * 32];
    __shared__ alignas(16) u16 Bs[128 * 32];
    const int tid = threadIdx.x;
    const int lane = tid & 63;
    const int wv = tid >> 6, wr = wv >> 1, wc = wv & 1;
    const int fr = lane & 15, fg = lane >> 4;
    const int m0 = blockIdx.y * 128, n0 = blockIdx.x * 128;
    const int srow = tid >> 2, scol = (tid & 3) * 8;
    const u16* Ag = A + (size_t)(m0 + srow) * K + scol;
    const u16* Bg = Bt + (size_t)(n0 + srow) * K + scol;
    f32x4 acc[4][4] = {};
    for (int kt = 0; kt < K; kt += 32) {
        gload_lds16(Ag + kt, &As[tid * 8]);
        gload_lds16(Ag + (size_t)64 * K + kt, &As[2048 + tid * 8]);
        gload_lds16(Bg + kt, &Bs[tid * 8]);
        gload_lds16(Bg + (size_t)64 * K + kt, &Bs[2048 + tid * 8]);
        asm volatile("s_waitcnt vmcnt(0)" ::: "memory");
        __syncthreads();
        bf16x8 af[4], bfv[4];
#pragma unroll
        for (int m = 0; m < 4; ++m)
            af[m] = *(const bf16x8*)&As[(wr * 64 + m * 16 + fr) * 32 + fg * 8];
#pragma unroll
        for (int n = 0; n < 4; ++n)
            bfv[n] = *(const bf16x8*)&Bs[(wc * 64 + n * 16 + fr) * 32 + fg * 8];
#pragma unroll
        for (int m = 0; m < 4; ++m)
#pragma unroll
            for (int n = 0; n < 4; ++n)
                acc[m][n] = mfma16(af[m], bfv[n], acc[m][n]);
        __syncthreads();
    }
#pragma unroll
    for (int m = 0; m < 4; ++m) {
#pragma unroll
        for (int n = 0; n < 4; ++n) {
#pragma unroll
            for (int r = 0; r < 4; ++r) {
                int row = m0 + wr * 64 + m * 16 + fg * 4 + r;
                int col = n0 + wc * 64 + n * 16 + fr;
                float v = acc[m][n][r];
                if (MODE == 0) {
                    float bias = (col < 2048) ? bq[col]
                               : (col < 2560) ? bk[col - 2048] : bv[col - 2560];
                    Cb[(size_t)row * N + col] = f2bf(v + bias);
                } else {
                    Cf[(size_t)row * N + col] = v;
                }
            }
        }
    }
}

// ---------- RoPE sin/cos table: tbl[bs][d] = (sin, cos)(pos(bs) * invfreq(d)) ----------
__global__ __launch_bounds__(256) void build_rope_tbl(
    const int* __restrict__ pos_ids, float2* __restrict__ tbl)
{
    int idx = blockIdx.x * 256 + threadIdx.x;     // 4096*64
    int bs = idx >> 6, d = idx & 63;
    float pos = (float)pos_ids[bs];
    float ang = pos * __expf(-(float)d * 0.1439115683121279f);
    tbl[idx] = make_float2(sinf(ang), cosf(ang));
}

// ---------- RoPE + relayout (Q, K), vectorized bf16x8 ----------
// block 192: t<128 -> Q heads, 128..159 -> K heads
__global__ __launch_bounds__(192) void rope_layout_kernel(
    const u16* __restrict__ qkvb, const float2* __restrict__ tbl,
    u16* __restrict__ Qs, u16* __restrict__ Ks)
{
    const int bs = blockIdx.x;
    const int b = bs >> 11, s = bs & 2047;
    const int t = threadIdx.x;
    if (t >= 160) return;
    const bool isq = (t < 128);
    const int hh = isq ? (t >> 3) : ((t - 128) >> 3);
    const int j = t & 7;
    const float scale = isq ? 0.08838834764831845f : 1.0f;
    const u16* src = qkvb + (size_t)bs * 3072 + (isq ? 0 : 2048) + hh * 128 + j * 8;
    u16* dst = (isq ? Qs + ((size_t)(b * 16 + hh) * 2048 + s) * 128
                    : Ks + ((size_t)(b * 4 + hh) * 2048 + s) * 128) + j * 8;
    const float2* tb = tbl + (size_t)bs * 64 + j * 8;
    u16x8 lo = *(const u16x8*)src;
    u16x8 hi = *(const u16x8*)(src + 64);
    u16x8 olo, ohi;
#pragma unroll
    for (int e = 0; e < 8; ++e) {
        float2 sc = tb[e];
        float xl = bf2f(lo[e]), xh = bf2f(hi[e]);
        olo[e] = f2bf((xl * sc.y - xh * sc.x) * scale);
        ohi[e] = f2bf((xh * sc.y + xl * sc.x) * scale);
    }
    *(u16x8*)dst = olo;
    *(u16x8*)(dst + 64) = ohi;
}

// ---------- V transpose: qkvb[.][2560+h*128+d] -> Vt [B][4][128][S] ----------
__global__ __launch_bounds__(256) void v_transpose_kernel(
    const u16* __restrict__ qkvb, u16* __restrict__ Vt)
{
    __shared__ u16 tl[64][136];
    const int s0 = blockIdx.x * 64, hh = blockIdx.y, b = blockIdx.z;
    const int tid = threadIdx.x;
    {
        const int r = tid >> 4, c = (tid & 15) * 8;
        const u16* src = qkvb + (size_t)(b * 2048 + s0) * 3072 + 2560 + hh * 128 + c;
#pragma unroll
        for (int i = 0; i < 4; ++i)
            *(bf16x8*)&tl[i * 16 + r][c] = *(const bf16x8*)&src[(size_t)(i * 16 + r) * 3072];
    }
    __syncthreads();
    {
        const int d = tid >> 3, sc = (tid & 7) * 8;
        u16* dst = Vt + ((size_t)(b * 4 + hh) * 128) * 2048 + s0;
#pragma unroll
        for (int i = 0; i < 4; ++i) {
            u16x8 vv;
#pragma unroll
            for (int e = 0; e < 8; ++e) vv[e] = tl[sc + e][i * 32 + d];
            *(u16x8*)&dst[(size_t)(i * 32 + d) * 2048 + sc] = vv;
        }
    }
}

// ---------- flash attention, swapped-operand 32x32 MFMA ----------
// block = 128 q rows (4 waves x 32 q), KVBLK = 64, K/V dbuf LDS. grid (16,16,2)
// S^T = mfma32(K, Q): lane owns q = q0w + (lane&31); kv over regs.
// O^T = mfma32(V^T, P^T): lane owns same q; d over regs.
__global__ __launch_bounds__(256, 2) void attn_kernel(
    const u16* __restrict__ Qs, const u16* __restrict__ Ks,
    const u16* __restrict__ Vt, u16* __restrict__ Aout)
{
    __shared__ alignas(16) u16 Klds[2][64 * 128];   // 64 kv x 128 d, swz (row&15)
    __shared__ alignas(16) u16 Vlds[2][128 * 64];   // 128 d x 64 kv, swz (row&7)
    const int tid = threadIdx.x;
    const int lane = tid & 63, w = tid >> 6;
    const int q5 = lane & 31, hi = lane >> 5;
    const int h = blockIdx.y, b = blockIdx.z;
    const int kvh = h >> 2;
    const int q0b = blockIdx.x * 128;
    const int q0w = q0b + w * 32;
    const int q = q0w + q5;
    const u16* Qb = Qs + ((size_t)(b * 16 + h) * 2048) * 128;
    const u16* Kb = Ks + ((size_t)(b * 4 + kvh) * 2048) * 128;
    const u16* Vb = Vt + ((size_t)(b * 4 + kvh) * 128) * 2048;

    // Q fragments: B-operand, lane holds Q[q][dd*16 + hi*8 + j]
    bf16x8 qf[8];
#pragma unroll
    for (int dd = 0; dd < 8; ++dd)
        qf[dd] = *(const bf16x8*)&Qb[(size_t)q * 128 + dd * 16 + hi * 8];

    f32x16 o[4] = {};
    float m_run = -1e30f, l_run = 0.f;

    int k_lo = q0b - 1024; if (k_lo < 0) k_lo = 0;
    const int NT = (q0b + 128 - k_lo) / 64;

    // staging address precompute (pre-swizzled global source, linear LDS dest)
    const int kst_r = tid >> 4;                               // 0..15
    const int kst_c = ((tid & 15) ^ kst_r) * 8;               // swizzled col (u16)
    const int kst_d = (tid & 15) * 8;
    const int vst_r = tid >> 3;                               // 0..31
    const int vst_c = ((tid & 7) ^ (vst_r & 7)) * 8;
    const int vst_d = (tid & 7) * 8;

#define STAGE(buf, kt)                                                           \
    {                                                                            \
        _Pragma("unroll")                                                        \
        for (int i = 0; i < 4; ++i)                                              \
            gload_lds16(Kb + (size_t)((kt) + i * 16 + kst_r) * 128 + kst_c,      \
                        &Klds[buf][(i * 16 + kst_r) * 128 + kst_d]);             \
        _Pragma("unroll")                                                        \
        for (int i = 0; i < 4; ++i)                                              \
            gload_lds16(Vb + (size_t)(i * 32 + vst_r) * 2048 + (kt) + vst_c,     \
                        &Vlds[buf][(i * 32 + vst_r) * 64 + vst_d]);              \
    }

    int cur = 0;
    STAGE(0, k_lo);
    asm volatile("s_waitcnt vmcnt(0)" ::: "memory");
    __syncthreads();

    for (int t = 0; t < NT; ++t) {
        const int kt = k_lo + t * 64;
        if (t + 1 < NT) STAGE(cur ^ 1, kt + 64);
        const bool active = (kt <= q0w + 31) && (kt + 63 >= q0w - 1024);
        if (active) {
            const u16* Kl = &Klds[cur][0];
            const u16* Vl = &Vlds[cur][0];
            // ---- QK^T (swapped): s[kb] = S^T tile, lane col = q ----
            f32x16 s[2] = {};
            __builtin_amdgcn_s_setprio(1);
#pragma unroll
            for (int dd = 0; dd < 8; ++dd) {
#pragma unroll
                for (int kb = 0; kb < 2; ++kb) {
                    const int krow = kb * 32 + q5;
                    bf16x8 kf = *(const bf16x8*)
                        &Kl[krow * 128 + ((dd * 16 + hi * 8) ^ ((krow & 15) * 8))];
                    s[kb] = mfma32(kf, qf[dd], s[kb]);
                }
            }
            __builtin_amdgcn_s_setprio(0);
            // ---- masking (boundary tiles only; wave-uniform branch) ----
            const bool needHigh = (kt + 63) > q0w;            // causal edge
            const bool needLow  = kt < (q0w + 31 - 1024);     // window edge
            if (needHigh || needLow) {
                const int dqb = q - kt;
#pragma unroll
                for (int kb = 0; kb < 2; ++kb)
#pragma unroll
                    for (int r = 0; r < 16; ++r) {
                        const int kvl = kb * 32 + (r & 3) + 8 * (r >> 2) + 4 * hi;
                        const unsigned dq = (unsigned)(dqb - kvl);
                        if (dq > 1024u) s[kb][r] = -1e30f;
                    }
            }
            // ---- online softmax (lane-local row) ----
            float tm = s[0][0];
#pragma unroll
            for (int r = 1; r < 16; ++r) tm = fmaxf(tm, s[0][r]);
#pragma unroll
            for (int r = 0; r < 16; ++r) tm = fmaxf(tm, s[1][r]);
            tm = fmaxf(tm, __shfl_xor(tm, 32));
            const float mn = fmaxf(m_run, tm);
            const float sc = __expf(m_run - mn);
            m_run = mn;
            float ps = 0.f;
#pragma unroll
            for (int kb = 0; kb < 2; ++kb)
#pragma unroll
                for (int r = 0; r < 16; ++r) {
                    float p = __expf(s[kb][r] - mn);
                    s[kb][r] = p;
                    ps += p;
                }
            ps += __shfl_xor(ps, 32);
            l_run = l_run * sc + ps;
#pragma unroll
            for (int db = 0; db < 4; ++db)
#pragma unroll
                for (int r = 0; r < 16; ++r) o[db][r] *= sc;
            // ---- pack P -> PV B-operand fragments (in-register half swap) ----
            bf16x8 paf[4];
#pragma unroll
            for (int kb = 0; kb < 2; ++kb) {
#pragma unroll
                for (int kk = 0; kk < 2; ++kk) {
                    const int rb = kk * 8;
                    u32 pk0 = (u32)f2bf(s[kb][rb + 0]) | ((u32)f2bf(s[kb][rb + 1]) << 16);
                    u32 pk1 = (u32)f2bf(s[kb][rb + 2]) | ((u32)f2bf(s[kb][rb + 3]) << 16);
                    u32 pk2 = (u32)f2bf(s[kb][rb + 4]) | ((u32)f2bf(s[kb][rb + 5]) << 16);
                    u32 pk3 = (u32)f2bf(s[kb][rb + 6]) | ((u32)f2bf(s[kb][rb + 7]) << 16);
                    u32 pk2x = __shfl_xor(pk2, 32);
                    u32 pk3x = __shfl_xor(pk3, 32);
                    u32 pk0x = __shfl_xor(pk0, 32);
                    u32 pk1x = __shfl_xor(pk1, 32);
                    u32x4 fw;
                    fw[0] = hi ? pk2x : pk0;     // kv 0,1 | 8,9
                    fw[1] = hi ? pk3x : pk1;     // kv 2,3 | 10,11
                    fw[2] = hi ? pk2 : pk0x;     // kv 4,5 | 12,13
                    fw[3] = hi ? pk3 : pk1x;     // kv 6,7 | 14,15
                    paf[kb * 2 + kk] = *(bf16x8*)&fw;
                }
            }
            // ---- PV: o[db] (O^T) += mfma32(V^T-frag, P-frag) ----
            __builtin_amdgcn_s_setprio(1);
#pragma unroll
            for (int ks = 0; ks < 4; ++ks) {
#pragma unroll
                for (int db = 0; db < 4; ++db) {
                    const int vrow = db * 32 + q5;
                    bf16x8 vf = *(const bf16x8*)
                        &Vl[vrow * 64 + ((ks * 16 + hi * 8) ^ ((vrow & 7) * 8))];
                    o[db] = mfma32(vf, paf[ks], o[db]);
                }
            }
            __builtin_amdgcn_s_setprio(0);
        }
        asm volatile("s_waitcnt vmcnt(0)" ::: "memory");
        __syncthreads();
        cur ^= 1;
    }
#undef STAGE

    // ---- epilogue: normalize, store O (lane q fixed; d = db*32+8g+4hi+{0..3}) ----
    const float invl = 1.0f / l_run;
    u16* orow = Aout + ((size_t)b * 2048 + q) * 2048 + h * 128;
#pragma unroll
    for (int db = 0; db < 4; ++db)
#pragma unroll
        for (int g = 0; g < 4; ++g) {
            u16x4 pkv;
#pragma unroll
            for (int e = 0; e < 4; ++e) pkv[e] = f2bf(o[db][g * 4 + e] * invl);
            *(u16x4*)&orow[db * 32 + 8 * g + 4 * hi] = pkv;
        }
}

// ---------- launch ----------
extern "C" void kernel_launch(void* const* d_in, const int* in_sizes, int n_in,
                              void* d_out, int out_size, void* d_ws, size_t ws_size,
                              hipStream_t stream) {
    const float* hs  = (const float*)d_in[0];
    const int*   pos = (const int*)d_in[2];
    const float* Wq  = (const float*)d_in[3];
    const float* bq  = (const float*)d_in[4];
    const float* Wk  = (const float*)d_in[5];
    const float* bk  = (const float*)d_in[6];
    const float* Wv  = (const float*)d_in[7];
    const float* bv  = (const float*)d_in[8];
    const float* Wo  = (const float*)d_in[9];
    float* out = (float*)d_out;
    char* ws = (char*)d_ws;

    u16* hsb   = (u16*)(ws);                       // [4096][2048] (dead after gemm0)
    u16* WqkvT = (u16*)(ws + 16777216);            // [3072][2048]
    u16* WoT   = (u16*)(ws + 29360128);            // [2048][2048]
    u16* qkvb  = (u16*)(ws + 37748736);            // [4096][3072]
    u16* Qs    = (u16*)(ws + 62914560);            // [2][16][2048][128]
    u16* Ks    = (u16*)(ws + 79691776);            // [2][4][2048][128]
    u16* Vt    = (u16*)(ws + 83886080);            // [2][4][128][2048]
    u16* aout  = (u16*)(ws + 88080384);            // [4096][2048]
    float2* tbl = (float2*)(ws);                   // reuse hsb space after gemm0 (2 MB)

    cast_bf16_kernel<<<8192, 256, 0, stream>>>((const float4*)hs, hsb);
    transpose_cast_k<<<dim3(64, 64), dim3(32, 8), 0, stream>>>(Wq, WqkvT, 2048);
    transpose_cast_k<<<dim3(16, 64), dim3(32, 8), 0, stream>>>(Wk, WqkvT + (size_t)2048 * 2048, 512);
    transpose_cast_k<<<dim3(16, 64), dim3(32, 8), 0, stream>>>(Wv, WqkvT + (size_t)2560 * 2048, 512);
    transpose_cast_k<<<dim3(64, 64), dim3(32, 8), 0, stream>>>(Wo, WoT, 2048);

    gemm_bt<0><<<dim3(24, 32), 256, 0, stream>>>(hsb, WqkvT, qkvb, nullptr,
                                                 bq, bk, bv, 4096, 3072, 2048);
    build_rope_tbl<<<1024, 256, 0, stream>>>(pos, tbl);
    rope_layout_kernel<<<4096, 192, 0, stream>>>(qkvb, tbl, Qs, Ks);
    v_transpose_kernel<<<dim3(32, 4, 2), 256, 0, stream>>>(qkvb, Vt);
    attn_kernel<<<dim3(16, 16, 2), 256, 0, stream>>>(Qs, Ks, Vt, aout);
    gemm_bt<1><<<dim3(16, 32), 256, 0, stream>>>(aout, WoT, nullptr, out,
                                                 nullptr, nullptr, nullptr, 4096, 2048, 2048);
}

// Round 5
// 326.136 us; speedup vs baseline: 1.5984x; 1.0321x over previous
//
#include <hip/hip_runtime.h>

typedef unsigned short u16;
typedef unsigned int u32;
typedef __attribute__((ext_vector_type(8))) __bf16 bf16x8;
typedef __attribute__((ext_vector_type(8))) unsigned short u16x8;
typedef __attribute__((ext_vector_type(4))) unsigned short u16x4;
typedef __attribute__((ext_vector_type(4))) unsigned int u32x4;
typedef __attribute__((ext_vector_type(4))) float f32x4;
typedef __attribute__((ext_vector_type(16))) float f32x16;

// ---------- helpers ----------
__device__ inline u16 f2bf(float f) {
    union { float f; unsigned u; } v; v.f = f;
    unsigned r = v.u + 0x7fffu + ((v.u >> 16) & 1u);
    return (u16)(r >> 16);
}
__device__ inline float bf2f(u16 h) {
    union { unsigned u; float f; } v; v.u = ((unsigned)h) << 16;
    return v.f;
}
__device__ inline f32x4 mfma16(bf16x8 a, bf16x8 b, f32x4 c) {
    return __builtin_amdgcn_mfma_f32_16x16x32_bf16(a, b, c, 0, 0, 0);
}
__device__ inline f32x16 mfma32(bf16x8 a, bf16x8 b, f32x16 c) {
    return __builtin_amdgcn_mfma_f32_32x32x16_bf16(a, b, c, 0, 0, 0);
}
__device__ inline void gload_lds16(const u16* g, u16* l) {
    __builtin_amdgcn_global_load_lds(
        (const __attribute__((address_space(1))) void*)g,
        (__attribute__((address_space(3))) void*)l, 16, 0, 0);
}

// ---------- cast f32 -> bf16 (vectorized) ----------
__global__ __launch_bounds__(256) void cast_bf16_kernel(
    const float4* __restrict__ in, u16* __restrict__ out) {
    int i = blockIdx.x * 256 + threadIdx.x;
    float4 v = in[i];
    unsigned long long pk = (unsigned long long)f2bf(v.x)
        | ((unsigned long long)f2bf(v.y) << 16)
        | ((unsigned long long)f2bf(v.z) << 32)
        | ((unsigned long long)f2bf(v.w) << 48);
    *(unsigned long long*)(out + (size_t)i * 4) = pk;
}

// ---------- transpose + cast: in [2048][N] f32 -> out [N][2048] bf16 ----------
__global__ void transpose_cast_k(const float* __restrict__ in, u16* __restrict__ out, int N) {
    __shared__ float t[32][33];
    int n0 = blockIdx.x * 32, k0 = blockIdx.y * 32;
    int tx = threadIdx.x, ty = threadIdx.y;       // 32 x 8
#pragma unroll
    for (int r = 0; r < 32; r += 8)
        t[ty + r][tx] = in[(size_t)(k0 + ty + r) * N + n0 + tx];
    __syncthreads();
#pragma unroll
    for (int r = 0; r < 32; r += 8)
        out[(size_t)(n0 + ty + r) * 2048 + k0 + tx] = f2bf(t[tx][ty + r]);
}

// ---------- GEMM (8-wave, BM=256 BN=128 BK=64, 3-ring LDS, counted vmcnt) ----------
// C[M][N] = A[M][K] * Bt[N][K]^T (+bias). MODE 0: bf16 out + qkv bias; 1: f32 out.
// Waves 4M x 2N; per-wave 64x64 out (4x4 16x16 frags). LDS: 3 x (A 32KB + B 16KB).
// Swizzle: 16B granule g stored at g^(row&7); staged via pre-swizzled global src.
template<int MODE>
__global__ __launch_bounds__(512) void gemm8(
    const u16* __restrict__ A, const u16* __restrict__ Bt,
    u16* __restrict__ Cb, float* __restrict__ Cf,
    const float* __restrict__ bq, const float* __restrict__ bk,
    const float* __restrict__ bv, int M, int N, int K)
{
    __shared__ alignas(16) u16 ring[3][24576];   // per buf: A[256][64] @0, B[128][64] @16384
    const int tid = threadIdx.x;
    const int lane = tid & 63;
    const int wv = tid >> 6;
    const int wr = wv >> 1, wc = wv & 1;         // 4M x 2N
    const int fr = lane & 15, fg = lane >> 4;
    const int m0 = blockIdx.y * 256, n0 = blockIdx.x * 128;
    const int NT = K >> 6;
    const int str = tid >> 3;                    // staging row within 64-chunk
    const int stg = tid & 7;                     // staging granule

    f32x4 acc[4][4] = {};
    bf16x8 areg[2][2][2], breg[2][2][2];         // [half][frag][kk]

#define STAGE_A(buf, kt, j) { \
    const int r_ = (j) * 64 + str; \
    gload_lds16(A + (size_t)(m0 + r_) * K + (kt) + ((stg ^ (r_ & 7)) * 8), \
                &ring[buf][r_ * 64 + stg * 8]); }
#define STAGE_B(buf, kt, j) { \
    const int r_ = (j) * 64 + str; \
    gload_lds16(Bt + (size_t)(n0 + r_) * K + (kt) + ((stg ^ (r_ & 7)) * 8), \
                &ring[buf][16384 + r_ * 64 + stg * 8]); }
#define DS_A(h) { _Pragma("unroll") for (int mf = 0; mf < 2; ++mf) \
    _Pragma("unroll") for (int kk = 0; kk < 2; ++kk) { \
        const int r_ = wr * 64 + ((h) * 2 + mf) * 16 + fr; \
        const int sg_ = (kk * 4 + fg) ^ (r_ & 7); \
        areg[h][mf][kk] = *(const bf16x8*)&Ac[r_ * 64 + sg_ * 8]; } }
#define DS_B(h) { _Pragma("unroll") for (int nf = 0; nf < 2; ++nf) \
    _Pragma("unroll") for (int kk = 0; kk < 2; ++kk) { \
        const int r_ = wc * 64 + ((h) * 2 + nf) * 16 + fr; \
        const int sg_ = (kk * 4 + fg) ^ (r_ & 7); \
        breg[h][nf][kk] = *(const bf16x8*)&Bc[16384 + r_ * 64 + sg_ * 8]; } }
#define MFMAQ(mh, nh) { \
    __builtin_amdgcn_s_setprio(1); \
    _Pragma("unroll") for (int kk = 0; kk < 2; ++kk) \
    _Pragma("unroll") for (int mf = 0; mf < 2; ++mf) \
    _Pragma("unroll") for (int nf = 0; nf < 2; ++nf) \
        acc[(mh) * 2 + mf][(nh) * 2 + nf] = \
            mfma16(areg[mh][mf][kk], breg[nh][nf][kk], acc[(mh) * 2 + mf][(nh) * 2 + nf]); \
    __builtin_amdgcn_s_setprio(0); }
#define BAR() __builtin_amdgcn_s_barrier()
#define LGKM0() { asm volatile("s_waitcnt lgkmcnt(0)" ::: "memory"); \
                  __builtin_amdgcn_sched_barrier(0); }

    // prologue: stage tiles 0,1 (6 loads each)
#pragma unroll
    for (int j = 0; j < 4; ++j) STAGE_A(0, 0, j)
#pragma unroll
    for (int j = 0; j < 2; ++j) STAGE_B(0, 0, j)
#pragma unroll
    for (int j = 0; j < 4; ++j) STAGE_A(1, 64, j)
#pragma unroll
    for (int j = 0; j < 2; ++j) STAGE_B(1, 64, j)
    asm volatile("s_waitcnt vmcnt(6)" ::: "memory");   // own tile-0 loads landed
    BAR();

    int cur = 0;
    for (int t = 0; t < NT; ++t) {
        const u16* Ac = ring[cur];
        const u16* Bc = ring[cur];
        int nb = cur + 2; if (nb >= 3) nb -= 3;
        const int kn = (t + 2) << 6;
        const bool ds = (t + 2) < NT;
        // P1: A-half0 + B-half0 reads; stage next A chunks 0,1
        DS_A(0) DS_B(0)
        if (ds) { STAGE_A(nb, kn, 0) STAGE_A(nb, kn, 1) }
        BAR(); LGKM0(); MFMAQ(0, 0); BAR();
        // P2: B-half1 reads; stage next A chunks 2,3
        DS_B(1)
        if (ds) { STAGE_A(nb, kn, 2) STAGE_A(nb, kn, 3) }
        BAR(); LGKM0(); MFMAQ(0, 1); BAR();
        // P3: A-half1 reads; stage next B chunks 0,1
        DS_A(1)
        if (ds) { STAGE_B(nb, kn, 0) STAGE_B(nb, kn, 1) }
        BAR(); LGKM0(); MFMAQ(1, 1); BAR();
        // P4: no reads (regs live); wait next tile's loads (counted, never 0 mid-loop)
        MFMAQ(1, 0);
        if (ds) { asm volatile("s_waitcnt vmcnt(6)" ::: "memory"); }
        else if (t + 2 == NT) { asm volatile("s_waitcnt vmcnt(0)" ::: "memory"); }
        BAR();
        cur = (cur + 1 == 3) ? 0 : cur + 1;
    }
#undef STAGE_A
#undef STAGE_B
#undef DS_A
#undef DS_B
#undef MFMAQ
#undef BAR
#undef LGKM0

#pragma unroll
    for (int mf = 0; mf < 4; ++mf) {
#pragma unroll
        for (int nf = 0; nf < 4; ++nf) {
#pragma unroll
            for (int r = 0; r < 4; ++r) {
                int row = m0 + wr * 64 + mf * 16 + fg * 4 + r;
                int col = n0 + wc * 64 + nf * 16 + fr;
                float v = acc[mf][nf][r];
                if (MODE == 0) {
                    float bias = (col < 2048) ? bq[col]
                               : (col < 2560) ? bk[col - 2048] : bv[col - 2560];
                    Cb[(size_t)row * N + col] = f2bf(v + bias);
                } else {
                    Cf[(size_t)row * N + col] = v;
                }
            }
        }
    }
}

// ---------- RoPE sin/cos table ----------
__global__ __launch_bounds__(256) void build_rope_tbl(
    const int* __restrict__ pos_ids, float2* __restrict__ tbl)
{
    int idx = blockIdx.x * 256 + threadIdx.x;     // 4096*64
    int bs = idx >> 6, d = idx & 63;
    float pos = (float)pos_ids[bs];
    float ang = pos * __expf(-(float)d * 0.1439115683121279f);
    tbl[idx] = make_float2(sinf(ang), cosf(ang));
}

// ---------- RoPE + relayout (Q, K), vectorized bf16x8 ----------
__global__ __launch_bounds__(192) void rope_layout_kernel(
    const u16* __restrict__ qkvb, const float2* __restrict__ tbl,
    u16* __restrict__ Qs, u16* __restrict__ Ks)
{
    const int bs = blockIdx.x;
    const int b = bs >> 11, s = bs & 2047;
    const int t = threadIdx.x;
    if (t >= 160) return;
    const bool isq = (t < 128);
    const int hh = isq ? (t >> 3) : ((t - 128) >> 3);
    const int j = t & 7;
    const float scale = isq ? 0.08838834764831845f : 1.0f;
    const u16* src = qkvb + (size_t)bs * 3072 + (isq ? 0 : 2048) + hh * 128 + j * 8;
    u16* dst = (isq ? Qs + ((size_t)(b * 16 + hh) * 2048 + s) * 128
                    : Ks + ((size_t)(b * 4 + hh) * 2048 + s) * 128) + j * 8;
    const float2* tb = tbl + (size_t)bs * 64 + j * 8;
    u16x8 lo = *(const u16x8*)src;
    u16x8 hi = *(const u16x8*)(src + 64);
    u16x8 olo, ohi;
#pragma unroll
    for (int e = 0; e < 8; ++e) {
        float2 sc = tb[e];
        float xl = bf2f(lo[e]), xh = bf2f(hi[e]);
        olo[e] = f2bf((xl * sc.y - xh * sc.x) * scale);
        ohi[e] = f2bf((xh * sc.y + xl * sc.x) * scale);
    }
    *(u16x8*)dst = olo;
    *(u16x8*)(dst + 64) = ohi;
}

// ---------- V transpose: qkvb[.][2560+h*128+d] -> Vt [B][4][128][S] ----------
__global__ __launch_bounds__(256) void v_transpose_kernel(
    const u16* __restrict__ qkvb, u16* __restrict__ Vt)
{
    __shared__ u16 tl[64][136];
    const int s0 = blockIdx.x * 64, hh = blockIdx.y, b = blockIdx.z;
    const int tid = threadIdx.x;
    {
        const int r = tid >> 4, c = (tid & 15) * 8;
        const u16* src = qkvb + (size_t)(b * 2048 + s0) * 3072 + 2560 + hh * 128 + c;
#pragma unroll
        for (int i = 0; i < 4; ++i)
            *(bf16x8*)&tl[i * 16 + r][c] = *(const bf16x8*)&src[(size_t)(i * 16 + r) * 3072];
    }
    __syncthreads();
    {
        const int d = tid >> 3, sc = (tid & 7) * 8;
        u16* dst = Vt + ((size_t)(b * 4 + hh) * 128) * 2048 + s0;
#pragma unroll
        for (int i = 0; i < 4; ++i) {
            u16x8 vv;
#pragma unroll
            for (int e = 0; e < 8; ++e) vv[e] = tl[sc + e][i * 32 + d];
            *(u16x8*)&dst[(size_t)(i * 32 + d) * 2048 + sc] = vv;
        }
    }
}

// ---------- flash attention, swapped-operand 32x32 MFMA ----------
__global__ __launch_bounds__(256, 2) void attn_kernel(
    const u16* __restrict__ Qs, const u16* __restrict__ Ks,
    const u16* __restrict__ Vt, u16* __restrict__ Aout)
{
    __shared__ alignas(16) u16 Klds[2][64 * 128];   // 64 kv x 128 d, swz (row&15)
    __shared__ alignas(16) u16 Vlds[2][128 * 64];   // 128 d x 64 kv, swz (row&7)
    const int tid = threadIdx.x;
    const int lane = tid & 63, w = tid >> 6;
    const int q5 = lane & 31, hi = lane >> 5;
    const int h = blockIdx.y, b = blockIdx.z;
    const int kvh = h >> 2;
    const int q0b = blockIdx.x * 128;
    const int q0w = q0b + w * 32;
    const int q = q0w + q5;
    const u16* Qb = Qs + ((size_t)(b * 16 + h) * 2048) * 128;
    const u16* Kb = Ks + ((size_t)(b * 4 + kvh) * 2048) * 128;
    const u16* Vb = Vt + ((size_t)(b * 4 + kvh) * 128) * 2048;

    bf16x8 qf[8];
#pragma unroll
    for (int dd = 0; dd < 8; ++dd)
        qf[dd] = *(const bf16x8*)&Qb[(size_t)q * 128 + dd * 16 + hi * 8];

    f32x16 o[4] = {};
    float m_run = -1e30f, l_run = 0.f;

    int k_lo = q0b - 1024; if (k_lo < 0) k_lo = 0;
    const int NT = (q0b + 128 - k_lo) / 64;

    const int kst_r = tid >> 4;
    const int kst_c = ((tid & 15) ^ kst_r) * 8;
    const int kst_d = (tid & 15) * 8;
    const int vst_r = tid >> 3;
    const int vst_c = ((tid & 7) ^ (vst_r & 7)) * 8;
    const int vst_d = (tid & 7) * 8;

#define STAGE(buf, kt)                                                           \
    {                                                                            \
        _Pragma("unroll")                                                        \
        for (int i = 0; i < 4; ++i)                                              \
            gload_lds16(Kb + (size_t)((kt) + i * 16 + kst_r) * 128 + kst_c,      \
                        &Klds[buf][(i * 16 + kst_r) * 128 + kst_d]);             \
        _Pragma("unroll")                                                        \
        for (int i = 0; i < 4; ++i)                                              \
            gload_lds16(Vb + (size_t)(i * 32 + vst_r) * 2048 + (kt) + vst_c,     \
                        &Vlds[buf][(i * 32 + vst_r) * 64 + vst_d]);              \
    }

    int cur = 0;
    STAGE(0, k_lo);
    asm volatile("s_waitcnt vmcnt(0)" ::: "memory");
    __syncthreads();

    for (int t = 0; t < NT; ++t) {
        const int kt = k_lo + t * 64;
        if (t + 1 < NT) STAGE(cur ^ 1, kt + 64);
        const bool active = (kt <= q0w + 31) && (kt + 63 >= q0w - 1024);
        if (active) {
            const u16* Kl = &Klds[cur][0];
            const u16* Vl = &Vlds[cur][0];
            f32x16 s[2] = {};
            __builtin_amdgcn_s_setprio(1);
#pragma unroll
            for (int dd = 0; dd < 8; ++dd) {
#pragma unroll
                for (int kb = 0; kb < 2; ++kb) {
                    const int krow = kb * 32 + q5;
                    bf16x8 kf = *(const bf16x8*)
                        &Kl[krow * 128 + ((dd * 16 + hi * 8) ^ ((krow & 15) * 8))];
                    s[kb] = mfma32(kf, qf[dd], s[kb]);
                }
            }
            __builtin_amdgcn_s_setprio(0);
            const bool needHigh = (kt + 63) > q0w;
            const bool needLow  = kt < (q0w + 31 - 1024);
            if (needHigh || needLow) {
                const int dqb = q - kt;
#pragma unroll
                for (int kb = 0; kb < 2; ++kb)
#pragma unroll
                    for (int r = 0; r < 16; ++r) {
                        const int kvl = kb * 32 + (r & 3) + 8 * (r >> 2) + 4 * hi;
                        const unsigned dq = (unsigned)(dqb - kvl);
                        if (dq > 1024u) s[kb][r] = -1e30f;
                    }
            }
            float tm = s[0][0];
#pragma unroll
            for (int r = 1; r < 16; ++r) tm = fmaxf(tm, s[0][r]);
#pragma unroll
            for (int r = 0; r < 16; ++r) tm = fmaxf(tm, s[1][r]);
            tm = fmaxf(tm, __shfl_xor(tm, 32));
            const float mn = fmaxf(m_run, tm);
            const float sc = __expf(m_run - mn);
            m_run = mn;
            float ps = 0.f;
#pragma unroll
            for (int kb = 0; kb < 2; ++kb)
#pragma unroll
                for (int r = 0; r < 16; ++r) {
                    float p = __expf(s[kb][r] - mn);
                    s[kb][r] = p;
                    ps += p;
                }
            ps += __shfl_xor(ps, 32);
            l_run = l_run * sc + ps;
#pragma unroll
            for (int db = 0; db < 4; ++db)
#pragma unroll
                for (int r = 0; r < 16; ++r) o[db][r] *= sc;
            bf16x8 paf[4];
#pragma unroll
            for (int kb = 0; kb < 2; ++kb) {
#pragma unroll
                for (int kk = 0; kk < 2; ++kk) {
                    const int rb = kk * 8;
                    u32 pk0 = (u32)f2bf(s[kb][rb + 0]) | ((u32)f2bf(s[kb][rb + 1]) << 16);
                    u32 pk1 = (u32)f2bf(s[kb][rb + 2]) | ((u32)f2bf(s[kb][rb + 3]) << 16);
                    u32 pk2 = (u32)f2bf(s[kb][rb + 4]) | ((u32)f2bf(s[kb][rb + 5]) << 16);
                    u32 pk3 = (u32)f2bf(s[kb][rb + 6]) | ((u32)f2bf(s[kb][rb + 7]) << 16);
                    u32 pk2x = __shfl_xor(pk2, 32);
                    u32 pk3x = __shfl_xor(pk3, 32);
                    u32 pk0x = __shfl_xor(pk0, 32);
                    u32 pk1x = __shfl_xor(pk1, 32);
                    u32x4 fw;
                    fw[0] = hi ? pk2x : pk0;
                    fw[1] = hi ? pk3x : pk1;
                    fw[2] = hi ? pk2 : pk0x;
                    fw[3] = hi ? pk3 : pk1x;
                    paf[kb * 2 + kk] = *(bf16x8*)&fw;
                }
            }
            __builtin_amdgcn_s_setprio(1);
#pragma unroll
            for (int ks = 0; ks < 4; ++ks) {
#pragma unroll
                for (int db = 0; db < 4; ++db) {
                    const int vrow = db * 32 + q5;
                    bf16x8 vf = *(const bf16x8*)
                        &Vl[vrow * 64 + ((ks * 16 + hi * 8) ^ ((vrow & 7) * 8))];
                    o[db] = mfma32(vf, paf[ks], o[db]);
                }
            }
            __builtin_amdgcn_s_setprio(0);
        }
        asm volatile("s_waitcnt vmcnt(0)" ::: "memory");
        __syncthreads();
        cur ^= 1;
    }
#undef STAGE

    const float invl = 1.0f / l_run;
    u16* orow = Aout + ((size_t)b * 2048 + q) * 2048 + h * 128;
#pragma unroll
    for (int db = 0; db < 4; ++db)
#pragma unroll
        for (int g = 0; g < 4; ++g) {
            u16x4 pkv;
#pragma unroll
            for (int e = 0; e < 4; ++e) pkv[e] = f2bf(o[db][g * 4 + e] * invl);
            *(u16x4*)&orow[db * 32 + 8 * g + 4 * hi] = pkv;
        }
}

// ---------- launch ----------
extern "C" void kernel_launch(void* const* d_in, const int* in_sizes, int n_in,
                              void* d_out, int out_size, void* d_ws, size_t ws_size,
                              hipStream_t stream) {
    const float* hs  = (const float*)d_in[0];
    const int*   pos = (const int*)d_in[2];
    const float* Wq  = (const float*)d_in[3];
    const float* bq  = (const float*)d_in[4];
    const float* Wk  = (const float*)d_in[5];
    const float* bk  = (const float*)d_in[6];
    const float* Wv  = (const float*)d_in[7];
    const float* bv  = (const float*)d_in[8];
    const float* Wo  = (const float*)d_in[9];
    float* out = (float*)d_out;
    char* ws = (char*)d_ws;

    u16* hsb   = (u16*)(ws);                       // [4096][2048] (dead after gemm0)
    u16* WqkvT = (u16*)(ws + 16777216);            // [3072][2048]
    u16* WoT   = (u16*)(ws + 29360128);            // [2048][2048]
    u16* qkvb  = (u16*)(ws + 37748736);            // [4096][3072]
    u16* Qs    = (u16*)(ws + 62914560);            // [2][16][2048][128]
    u16* Ks    = (u16*)(ws + 79691776);            // [2][4][2048][128]
    u16* Vt    = (u16*)(ws + 83886080);            // [2][4][128][2048]
    u16* aout  = (u16*)(ws + 88080384);            // [4096][2048]
    float2* tbl = (float2*)(ws);                   // reuse hsb space after gemm0

    cast_bf16_kernel<<<8192, 256, 0, stream>>>((const float4*)hs, hsb);
    transpose_cast_k<<<dim3(64, 64), dim3(32, 8), 0, stream>>>(Wq, WqkvT, 2048);
    transpose_cast_k<<<dim3(16, 64), dim3(32, 8), 0, stream>>>(Wk, WqkvT + (size_t)2048 * 2048, 512);
    transpose_cast_k<<<dim3(16, 64), dim3(32, 8), 0, stream>>>(Wv, WqkvT + (size_t)2560 * 2048, 512);
    transpose_cast_k<<<dim3(64, 64), dim3(32, 8), 0, stream>>>(Wo, WoT, 2048);

    gemm8<0><<<dim3(24, 16), 512, 0, stream>>>(hsb, WqkvT, qkvb, nullptr,
                                               bq, bk, bv, 4096, 3072, 2048);
    build_rope_tbl<<<1024, 256, 0, stream>>>(pos, tbl);
    rope_layout_kernel<<<4096, 192, 0, stream>>>(qkvb, tbl, Qs, Ks);
    v_transpose_kernel<<<dim3(32, 4, 2), 256, 0, stream>>>(qkvb, Vt);
    attn_kernel<<<dim3(16, 16, 2), 256, 0, stream>>>(Qs, Ks, Vt, aout);
    gemm8<1><<<dim3(16, 16), 512, 0, stream>>>(aout, WoT, nullptr, out,
                                               nullptr, nullptr, nullptr, 4096, 2048, 2048);
}